// Round 20
// baseline (106.457 us; speedup 1.0000x reference)
//
#include <hip/hip_runtime.h>
#include <math.h>

#define B_ 4
#define C_ 1024
#define T_ 1024
#define H_ 16
#define CH_ 64
#define BCT (B_ * C_ * T_)   // 4194304

typedef __attribute__((ext_vector_type(8))) short s16x8;
typedef __attribute__((ext_vector_type(4))) float f32x4;
typedef __attribute__((ext_vector_type(2))) float f32x2;
typedef unsigned short u16;
typedef unsigned char u8;

#define MFMA8(a, b, c)  __builtin_amdgcn_mfma_f32_16x16x32_fp8_fp8((a), (b), (c), 0, 0, 0)

extern "C" __device__ float __ocml_native_exp2_f32(float);

__device__ __forceinline__ u16 f2bf(float f) {
    union { float f; unsigned u; } v; v.f = f;
    unsigned r = (v.u + 0x7fffu + ((v.u >> 16) & 1u)) >> 16;   // RNE
    return (u16)r;
}

// HW fp8 pack/unpack (gfx940+)
__device__ __forceinline__ unsigned pk4_fp8(float a, float b, float c, float d) {
    int v = 0;
    v = __builtin_amdgcn_cvt_pk_fp8_f32(a, b, v, false);   // bytes 0,1
    v = __builtin_amdgcn_cvt_pk_fp8_f32(c, d, v, true);    // bytes 2,3
    return (unsigned)v;
}
__device__ __forceinline__ u8 f2fp8(float v) {
    return (u8)(__builtin_amdgcn_cvt_pk_fp8_f32(v, v, 0, false) & 0xff);
}

// async global->LDS, 16B per lane; LDS dest = wave-uniform base + lane*16
typedef __attribute__((address_space(3))) unsigned int lds_u32;
typedef __attribute__((address_space(1))) const unsigned int glb_u32;
__device__ __forceinline__ void glds16(const void* g, const void* l_wave_uniform) {
    __builtin_amdgcn_global_load_lds(
        (glb_u32*)(unsigned long long)g,
        (lds_u32*)(unsigned long long)l_wave_uniform, 16, 0, 0);
}

// counted-vmcnt barrier: keep N loads in flight across the barrier (T4)
#define WAIT_BARRIER(N)                                   \
    asm volatile("s_waitcnt vmcnt(" #N ")" ::: "memory"); \
    __builtin_amdgcn_s_barrier();                         \
    __builtin_amdgcn_sched_barrier(0)

// ---------------------------------------------------------------------------
// prep_kernel: lnT (768 blocks, 16-t chunks -> 3 blocks/CU) + wcvt (2048)
// + mask_tail (8).
// ---------------------------------------------------------------------------
__global__ __launch_bounds__(512) void prep_kernel(
    const float* __restrict__ xq, const float* __restrict__ xk, const float* __restrict__ xv,
    const float* __restrict__ wq3, const float* __restrict__ wk3, const float* __restrict__ wv3,
    const int* __restrict__ qm, const int* __restrict__ kvm,
    const float* __restrict__ qnw, const float* __restrict__ qnb,
    const float* __restrict__ knw, const float* __restrict__ knb,
    const float* __restrict__ vnw, const float* __restrict__ vnb,
    u8* __restrict__ oq, u8* __restrict__ ok, u8* __restrict__ ov,
    const float* __restrict__ w0, const float* __restrict__ w1,
    const float* __restrict__ w2, const float* __restrict__ w3,
    u8* __restrict__ o0, u8* __restrict__ o1, u8* __restrict__ o2, u8* __restrict__ o3,
    float* __restrict__ tail_out, int ntail)
{
    __shared__ __align__(16) u8 tile8[16 * 1040];     // [t][c] fp8x16, 16.6KB
    __shared__ float w3L[3072];                       // conv weights (12KB)
    __shared__ float redw1[8][20], redw2[8][20];      // per-wave partials
    __shared__ float musL[16], rssL[16];

    const int bid = blockIdx.x;
    if (bid >= 768) {
        if (bid >= 2816) {                              // ---- mask_tail
            int i = (bid - 2816) * 512 + threadIdx.x;
            if (i < ntail) tail_out[i] = (qm[i] != 0) ? 1.f : 0.f;
            return;
        }
        // ---- wcvt: 512 blocks per matrix, 4 floats/thread -> fp8 * 64
        const int b2 = bid - 768;
        const int mat = b2 >> 9;
        const int i = ((b2 & 511) * 512 + threadIdx.x) * 4;
        const float* __restrict__ w = (mat == 0) ? w0 : (mat == 1) ? w1
                                     : (mat == 2) ? w2 : w3;
        u8* __restrict__ o = (mat == 0) ? o0 : (mat == 1) ? o1
                            : (mat == 2) ? o2 : o3;
        float4 v = *(const float4*)&w[i];
        *(unsigned*)&o[i] = pk4_fp8(64.f * v.x, 64.f * v.y, 64.f * v.z, 64.f * v.w);
        return;
    }

    // ---- lnT: fused dwconv(k=3,pad=1)+mask -> channel-LN -> transpose fp8
    const int z = bid >> 6;                 // tensor*4 + b
    const int tensor = z >> 2, b = z & 3;
    const float* __restrict__ x   = (tensor == 0) ? xq  : (tensor == 1) ? xk  : xv;
    const float* __restrict__ w3c = (tensor == 0) ? wq3 : (tensor == 1) ? wk3 : wv3;
    const int* __restrict__ msk   = (tensor == 0) ? qm  : kvm;
    const float* __restrict__ wln = (tensor == 0) ? qnw : (tensor == 1) ? knw : vnw;
    const float* __restrict__ bln = (tensor == 0) ? qnb : (tensor == 1) ? knb : vnb;
    u8* __restrict__ xt = (tensor == 0) ? oq : (tensor == 1) ? ok : ov;

    const int t0 = (bid & 63) * 16;

    #pragma unroll
    for (int i = 0; i < 6; ++i) w3L[i * 512 + threadIdx.x] = w3c[i * 512 + threadIdx.x];
    __syncthreads();

    // pass 1: lane = (cs, tg); tg 0..3, cs 0..127; lane owns t = t0+4tg..+3
    // of channels c = cs + 128*i (8 iters).
    const int tg = threadIdx.x & 3, cs = threadIdx.x >> 2;
    const int tbase = t0 + 4 * tg;
    const int4 m4 = *(const int4*)&msk[b * T_ + tbase];
    const float mk0 = m4.x ? 1.f : 0.f;
    const float mk1 = m4.y ? 1.f : 0.f;
    const float mk2 = m4.z ? 1.f : 0.f;
    const float mk3 = m4.w ? 1.f : 0.f;

    float s1a[4] = {0.f, 0.f, 0.f, 0.f};
    float s2a[4] = {0.f, 0.f, 0.f, 0.f};

    #pragma unroll 4
    for (int i = 0; i < 8; ++i) {
        const int c = cs + 128 * i;
        const float* xr = x + ((size_t)(b * C_ + c)) * T_ + tbase;
        const float4 f = *(const float4*)xr;
        float pv = __shfl_up(f.w, 1);      // lane-1 = same cs, tg-1
        float nv = __shfl_down(f.x, 1);    // lane+1 = same cs, tg+1
        if (tg == 0) pv = (t0 > 0)        ? xr[-1] : 0.f;
        if (tg == 3) nv = (t0 + 16 < T_)  ? xr[4]  : 0.f;
        const float cw0 = w3L[3 * c], cw1 = w3L[3 * c + 1], cw2 = w3L[3 * c + 2];
        const float v0 = (cw0 * pv  + cw1 * f.x + cw2 * f.y) * mk0;
        const float v1 = (cw0 * f.x + cw1 * f.y + cw2 * f.z) * mk1;
        const float v2 = (cw0 * f.y + cw1 * f.z + cw2 * f.w) * mk2;
        const float v3 = (cw0 * f.z + cw1 * f.w + cw2 * nv ) * mk3;
        s1a[0] += v0; s2a[0] += v0 * v0;
        s1a[1] += v1; s2a[1] += v1 * v1;
        s1a[2] += v2; s2a[2] += v2 * v2;
        s1a[3] += v3; s2a[3] += v3 * v3;
        const unsigned pk = pk4_fp8(16.f * v0, 16.f * v1, 16.f * v2, 16.f * v3);
        tile8[(4 * tg + 0) * 1040 + c] = (u8)(pk);
        tile8[(4 * tg + 1) * 1040 + c] = (u8)(pk >> 8);
        tile8[(4 * tg + 2) * 1040 + c] = (u8)(pk >> 16);
        tile8[(4 * tg + 3) * 1040 + c] = (u8)(pk >> 24);
    }

    // reduction: cs occupies lane bits 2..5 within wave -> xor 4,8,16,32
    #pragma unroll
    for (int j = 0; j < 4; ++j) {
        s1a[j] += __shfl_xor(s1a[j], 4);
        s1a[j] += __shfl_xor(s1a[j], 8);
        s1a[j] += __shfl_xor(s1a[j], 16);
        s1a[j] += __shfl_xor(s1a[j], 32);
        s2a[j] += __shfl_xor(s2a[j], 4);
        s2a[j] += __shfl_xor(s2a[j], 8);
        s2a[j] += __shfl_xor(s2a[j], 16);
        s2a[j] += __shfl_xor(s2a[j], 32);
    }
    const int lane = threadIdx.x & 63, wv = threadIdx.x >> 6;
    if (lane < 4) {                                    // cs-in-wave == 0, tg = lane
        float4 a; a.x = s1a[0]; a.y = s1a[1]; a.z = s1a[2]; a.w = s1a[3];
        float4 q; q.x = s2a[0]; q.y = s2a[1]; q.z = s2a[2]; q.w = s2a[3];
        *(float4*)&redw1[wv][4 * lane] = a;
        *(float4*)&redw2[wv][4 * lane] = q;
    }
    __syncthreads();
    if (threadIdx.x < 16) {
        float a = 0.f, q2 = 0.f;
        #pragma unroll
        for (int w = 0; w < 8; ++w) { a += redw1[w][threadIdx.x]; q2 += redw2[w][threadIdx.x]; }
        float m_  = a  * (1.f / C_);
        float var = q2 * (1.f / C_) - m_ * m_;
        musL[threadIdx.x] = m_;
        rssL[threadIdx.x] = rsqrtf(var + 1e-5f);
    }
    __syncthreads();

    // pass 2: normalize from tile8, emit fp8 X^T (4 iters of 512 threads)
    #pragma unroll
    for (int it = 0; it < 4; ++it) {
        const int idx = it * 512 + threadIdx.x;
        const int tt = idx >> 7, c0 = (idx & 127) * 8;
        const uint2 pv8 = *(const uint2*)&tile8[tt * 1040 + c0];
        const f32x2 f01 = __builtin_amdgcn_cvt_pk_f32_fp8((int)pv8.x, false);
        const f32x2 f23 = __builtin_amdgcn_cvt_pk_f32_fp8((int)pv8.x, true);
        const f32x2 f45 = __builtin_amdgcn_cvt_pk_f32_fp8((int)pv8.y, false);
        const f32x2 f67 = __builtin_amdgcn_cvt_pk_f32_fp8((int)pv8.y, true);
        const float m_ = musL[tt], rv = rssL[tt];
        const float4 wv0 = *(const float4*)&wln[c0];
        const float4 wv1 = *(const float4*)&wln[c0 + 4];
        const float4 bv0 = *(const float4*)&bln[c0];
        const float4 bv1 = *(const float4*)&bln[c0 + 4];
        const float inv16 = 0.0625f;
        float fv0 = (f01[0] * inv16 - m_) * rv * wv0.x + bv0.x;
        float fv1 = (f01[1] * inv16 - m_) * rv * wv0.y + bv0.y;
        float fv2 = (f23[0] * inv16 - m_) * rv * wv0.z + bv0.z;
        float fv3 = (f23[1] * inv16 - m_) * rv * wv0.w + bv0.w;
        float fv4 = (f45[0] * inv16 - m_) * rv * wv1.x + bv1.x;
        float fv5 = (f45[1] * inv16 - m_) * rv * wv1.y + bv1.y;
        float fv6 = (f67[0] * inv16 - m_) * rv * wv1.z + bv1.z;
        float fv7 = (f67[1] * inv16 - m_) * rv * wv1.w + bv1.w;
        uint2 o;
        o.x = pk4_fp8(fv0, fv1, fv2, fv3);
        o.y = pk4_fp8(fv4, fv5, fv6, fv7);
        *(uint2*)&xt[((size_t)(b * T_ + t0 + tt)) * C_ + c0] = o;
    }
}

// ---------------------------------------------------------------------------
// fp8 MFMA GEMM (NT), 128x128 tile, BK=64 (r18-proven core).
// ---------------------------------------------------------------------------
__device__ __forceinline__ void stage_slab8(
    const u8* __restrict__ gA, const u8* __restrict__ gB,
    u8* lA, u8* lB, int k0, int wave, int lane)
{
    const int rl = lane >> 2, blk = lane & 3;
    #pragma unroll
    for (int i = 0; i < 2; ++i) {
        const int row = wave * 32 + 16 * i + rl;
        const int sb = ((blk ^ ((row >> 1) & 3)) * 16) + k0;
        glds16(gA + (size_t)row * C_ + sb, lA + (wave * 32 + 16 * i) * 64);
        glds16(gB + (size_t)row * C_ + sb, lB + (wave * 32 + 16 * i) * 64);
    }
}

// shared BK=64 fp8 main loop; OUT_F32: 0 = fp8-out (QKV), 1 = f32-out (out-proj)
template<int OUT_F32>
__device__ __forceinline__ void gemm8_core(
    const u8* __restrict__ Ab, const u8* __restrict__ Bb, void* __restrict__ D,
    const float* __restrict__ bias, const int* __restrict__ mask,
    float acc_scale, float scale, int bias_on_n, int m0, int n0)
{
    __shared__ __align__(16) u8 As[3][128 * 64];
    __shared__ __align__(16) u8 Bs[3][128 * 64];
    const int tid = threadIdx.x, lane = tid & 63, wave = tid >> 6;
    const int r = lane & 15, g = lane >> 4;
    const int wm = (wave >> 1) * 64, wn = (wave & 1) * 64;

    f32x4 acc[4][4];
    #pragma unroll
    for (int i = 0; i < 4; ++i)
        #pragma unroll
        for (int j = 0; j < 4; ++j) acc[i][j] = f32x4{0.f, 0.f, 0.f, 0.f};

    stage_slab8(Ab, Bb, As[0], Bs[0], 0, wave, lane);
    stage_slab8(Ab, Bb, As[1], Bs[1], 64, wave, lane);
    WAIT_BARRIER(4);

    const int NK = 16;
    int cur = 0;
    for (int kt = 0; kt < NK; ++kt) {
        int pre = cur + 2; if (pre >= 3) pre -= 3;
        if (kt + 2 < NK)
            stage_slab8(Ab, Bb, As[pre], Bs[pre], (kt + 2) * 64, wave, lane);
        #pragma unroll
        for (int kk = 0; kk < 2; ++kk) {
            long af[4], bf[4];
            #pragma unroll
            for (int mi = 0; mi < 4; ++mi) {
                const int row = wm + 16 * mi + r;
                const int jb = (2 * kk + (g >> 1)) ^ ((row >> 1) & 3);
                af[mi] = *(const long*)&As[cur][row * 64 + jb * 16 + (g & 1) * 8];
            }
            #pragma unroll
            for (int ni = 0; ni < 4; ++ni) {
                const int row = wn + 16 * ni + r;
                const int jb = (2 * kk + (g >> 1)) ^ ((row >> 1) & 3);
                bf[ni] = *(const long*)&Bs[cur][row * 64 + jb * 16 + (g & 1) * 8];
            }
            #pragma unroll
            for (int mi = 0; mi < 4; ++mi)
                #pragma unroll
                for (int ni = 0; ni < 4; ++ni)
                    acc[mi][ni] = MFMA8(af[mi], bf[ni], acc[mi][ni]);
        }
        if (kt + 1 < NK) {
            if (kt + 2 < NK) { WAIT_BARRIER(4); }
            else             { WAIT_BARRIER(0); }
        }
        cur = (cur == 2) ? 0 : cur + 1;
    }

    #pragma unroll
    for (int mi = 0; mi < 4; ++mi) {
        #pragma unroll
        for (int ni = 0; ni < 4; ++ni) {
            const int n = n0 + wn + 16 * ni + r;
            float mk = 1.f;
            if (mask) mk = (mask[n] != 0) ? 1.f : 0.f;
            #pragma unroll
            for (int i = 0; i < 4; ++i) {
                const int m = m0 + wm + 16 * mi + 4 * g + i;
                float v = acc[mi][ni][i] * acc_scale + (bias_on_n ? bias[n] : bias[m]);
                v *= scale * mk;
                if (OUT_F32) ((float*)D)[(size_t)m * 1024 + n] = v;
                else         ((u8*)D)[(size_t)m * 1024 + n] = f2fp8(v);
            }
        }
    }
}

// merged Q/K/V projection, 1-D grid 768, XCD-chunked remap (T1)
__global__ __launch_bounds__(256) void gemm_qkv_kernel(
    const u8* __restrict__ Xq, const u8* __restrict__ Xk, const u8* __restrict__ Xv,
    const u8* __restrict__ Wq, const u8* __restrict__ Wk, const u8* __restrict__ Wv,
    const float* __restrict__ bq, const float* __restrict__ bk, const float* __restrict__ bv,
    u8* __restrict__ Qt, u8* __restrict__ Kt, u8* __restrict__ Vb, const int* __restrict__ kvm)
{
    const int p = blockIdx.x;                      // 0..767
    const int lb = (p & 7) * 96 + (p >> 3);        // bijective (768 % 8 == 0)
    const int z = lb >> 6, yy = (lb >> 3) & 7, xx = lb & 7;
    const int tensor = z >> 2, b = z & 3;
    const size_t off = (size_t)b * (1024 * 1024);
    const float qkscale = 0.42466090f;             // sqrt(0.125*log2e)
    const u8* A = (tensor == 0) ? Xq + off : (tensor == 1) ? Xk + off : Wv;
    const u8* B = (tensor == 0) ? Wq       : (tensor == 1) ? Wk       : Xv + off;
    u8*      D = (tensor == 0) ? Qt + off : (tensor == 1) ? Kt + off : Vb + off;
    const float* bias = (tensor == 0) ? bq : (tensor == 1) ? bk : bv;
    const int* mask = (tensor == 2) ? kvm + (size_t)b * T_ : nullptr;
    const float scale = (tensor == 2) ? 1.f : qkscale;
    const int m0 = yy * 128, n0 = xx * 128;
    gemm8_core<0>(A + (size_t)m0 * C_, B + (size_t)n0 * C_, D,
                  bias, mask, 0.015625f, scale, tensor != 2, m0, n0);
}

// out-proj: fp8 BK=64 core, f32 output.  att fp8 x16, wp fp8 x64 ->
// acc_scale = 1/1024.
__global__ __launch_bounds__(256) void gemm_out_kernel(
    const u8* __restrict__ Wp, const u8* __restrict__ att,
    const float* __restrict__ bp, float* __restrict__ out, const int* __restrict__ qm)
{
    const int p = blockIdx.x;                      // 0..255
    const int lb = (p & 7) * 32 + (p >> 3);        // bijective (256 % 8 == 0)
    const int b = lb >> 6, yy = (lb >> 3) & 7, xx = lb & 7;
    const size_t off = (size_t)b * (1024 * 1024);
    const int m0 = yy * 128, n0 = xx * 128;
    gemm8_core<1>(Wp + (size_t)m0 * C_, att + off + (size_t)n0 * C_, out + off,
                  bp, qm + (size_t)b * T_, 1.f / 1024.f, 1.f, 0, m0, n0);
}

// ---------------------------------------------------------------------------
// fp8 MFMA flash attention (r19-proven, unchanged).
// ---------------------------------------------------------------------------
__global__ __launch_bounds__(256) void attn_mfma_kernel(
    const u8* __restrict__ Qt, const u8* __restrict__ Kt, const u8* __restrict__ Vb,
    u8* __restrict__ att)
{
    const int p = blockIdx.x;                      // 0..511
    const int lb = (p & 7) * 64 + (p >> 3);        // bijective (512 % 8 == 0)
    const int bh = lb >> 3, sblk = lb & 7;
    const int b = bh >> 4, h = bh & 15;
    const int lane = threadIdx.x & 63, wave = threadIdx.x >> 6;
    const int r = lane & 15, g = lane >> 4;
    const int hofs = h * 64;
    const int s0 = sblk * 128 + wave * 16;         // second tile at s0+64

    __shared__ __align__(16) u8 Ks[3][64 * 64];    // [t][ch] 4KB
    __shared__ __align__(16) u8 Vs[3][64 * 64];    // [ch][t] 4KB
    __shared__ __align__(16) u8 P8[4][2][16 * 72];

    const u8* qb0 = Qt + ((size_t)(b * T_ + s0 + r)) * C_ + hofs + g * 8;
    const long qf00 = *(const long*)(qb0);
    const long qf01 = *(const long*)(qb0 + 32);
    const long qf10 = *(const long*)(qb0 + (size_t)64 * C_);
    const long qf11 = *(const long*)(qb0 + (size_t)64 * C_ + 32);

    const int rr = 16 * wave + (lane >> 2);
    const int sb16 = ((lane & 3) ^ ((rr >> 1) & 3)) * 16;
    const u8* kg = Kt + ((size_t)(b * T_)) * C_ + hofs;
    const u8* vg = Vb + ((size_t)(b * C_ + hofs)) * T_;

    auto stage = [&](int buf, int t0) {
        glds16(kg + (size_t)(t0 + rr) * C_ + sb16, &Ks[buf][(16 * wave) * 64]);
        glds16(vg + (size_t)rr * T_ + t0 + sb16,   &Vs[buf][(16 * wave) * 64]);
    };

    f32x4 acc0[4], acc1[4];
    #pragma unroll
    for (int ci = 0; ci < 4; ++ci) {
        acc0[ci] = f32x4{0.f, 0.f, 0.f, 0.f};
        acc1[ci] = f32x4{0.f, 0.f, 0.f, 0.f};
    }
    float l0 = 0.f, l1 = 0.f;
    u8* pw0 = &P8[wave][0][0];
    u8* pw1 = &P8[wave][1][0];

    stage(0, 0);
    stage(1, 64);
    WAIT_BARRIER(2);

    const int NT = T_ / 64;
    int cur = 0;
    for (int it = 0; it < NT; ++it) {
        int pre = cur + 2; if (pre >= 3) pre -= 3;
        if (it + 2 < NT) stage(pre, (it + 2) * 64);

        const u8* ks = Ks[cur];
        f32x4 st0[4], st1[4];
        __builtin_amdgcn_s_setprio(1);
        #pragma unroll
        for (int tt = 0; tt < 4; ++tt) {
            const int rowk = 16 * tt + r;
            const int ph = (rowk >> 1) & 3;
            const long ka = *(const long*)
                &ks[rowk * 64 + (((g >> 1) ^ ph) * 16 + (g & 1) * 8)];
            const long kb = *(const long*)
                &ks[rowk * 64 + (((2 + (g >> 1)) ^ ph) * 16 + (g & 1) * 8)];
            f32x4 sa = f32x4{0.f, 0.f, 0.f, 0.f};
            sa = MFMA8(ka, qf00, sa); sa = MFMA8(kb, qf01, sa); st0[tt] = sa;
            f32x4 sb = f32x4{0.f, 0.f, 0.f, 0.f};
            sb = MFMA8(ka, qf10, sb); sb = MFMA8(kb, qf11, sb); st1[tt] = sb;
        }
        __builtin_amdgcn_s_setprio(0);

        #pragma unroll
        for (int tt = 0; tt < 4; ++tt) {
            float a0 = __ocml_native_exp2_f32(st0[tt][0]);
            float a1 = __ocml_native_exp2_f32(st0[tt][1]);
            float a2 = __ocml_native_exp2_f32(st0[tt][2]);
            float a3 = __ocml_native_exp2_f32(st0[tt][3]);
            l0 += (a0 + a1) + (a2 + a3);
            *(unsigned*)&pw0[r * 72 + 16 * tt + 4 * g] = pk4_fp8(a0, a1, a2, a3);
            float b0 = __ocml_native_exp2_f32(st1[tt][0]);
            float b1 = __ocml_native_exp2_f32(st1[tt][1]);
            float b2 = __ocml_native_exp2_f32(st1[tt][2]);
            float b3 = __ocml_native_exp2_f32(st1[tt][3]);
            l1 += (b0 + b1) + (b2 + b3);
            *(unsigned*)&pw1[r * 72 + 16 * tt + 4 * g] = pk4_fp8(b0, b1, b2, b3);
        }

        const u8* vs = Vs[cur];
        __builtin_amdgcn_s_setprio(1);
        #pragma unroll
        for (int kk = 0; kk < 2; ++kk) {
            const long pa0 = *(const long*)&pw0[r * 72 + 32 * kk + 8 * g];
            const long pa1 = *(const long*)&pw1[r * 72 + 32 * kk + 8 * g];
            #pragma unroll
            for (int ci = 0; ci < 4; ++ci) {
                const int rowv = 16 * ci + r;
                const int pv_ = (rowv >> 1) & 3;
                const long vf = *(const long*)
                    &vs[rowv * 64 + (((2 * kk + (g >> 1)) ^ pv_) * 16 + (g & 1) * 8)];
                acc0[ci] = MFMA8(pa0, vf, acc0[ci]);
                acc1[ci] = MFMA8(pa1, vf, acc1[ci]);
            }
        }
        __builtin_amdgcn_s_setprio(0);

        if (it + 1 < NT) {
            if (it + 2 < NT) { WAIT_BARRIER(2); }
            else             { WAIT_BARRIER(0); }
        }
        cur = (cur == 2) ? 0 : cur + 1;
    }

    l0 += __shfl_xor(l0, 16); l0 += __shfl_xor(l0, 32);
    l1 += __shfl_xor(l1, 16); l1 += __shfl_xor(l1, 32);
    // att emitted as fp8 x16 (folded 1/l): inv = 16/l
    const float inv0 = 16.f / l0, inv1 = 16.f / l1;
    const float i00 = __shfl(inv0, 4 * g + 0), i01 = __shfl(inv0, 4 * g + 1);
    const float i02 = __shfl(inv0, 4 * g + 2), i03 = __shfl(inv0, 4 * g + 3);
    const float i10 = __shfl(inv1, 4 * g + 0), i11 = __shfl(inv1, 4 * g + 1);
    const float i12 = __shfl(inv1, 4 * g + 2), i13 = __shfl(inv1, 4 * g + 3);

    u8* ob = att + ((size_t)(b * T_ + s0 + 4 * g)) * C_ + hofs + r;
    #pragma unroll
    for (int ci = 0; ci < 4; ++ci) {
        ob[(size_t)0 * C_ + ci * 16] = f2fp8(acc0[ci][0] * i00);
        ob[(size_t)1 * C_ + ci * 16] = f2fp8(acc0[ci][1] * i01);
        ob[(size_t)2 * C_ + ci * 16] = f2fp8(acc0[ci][2] * i02);
        ob[(size_t)3 * C_ + ci * 16] = f2fp8(acc0[ci][3] * i03);
    }
    u8* ob1 = ob + (size_t)64 * C_;
    #pragma unroll
    for (int ci = 0; ci < 4; ++ci) {
        ob1[(size_t)0 * C_ + ci * 16] = f2fp8(acc1[ci][0] * i10);
        ob1[(size_t)1 * C_ + ci * 16] = f2fp8(acc1[ci][1] * i11);
        ob1[(size_t)2 * C_ + ci * 16] = f2fp8(acc1[ci][2] * i12);
        ob1[(size_t)3 * C_ + ci * 16] = f2fp8(acc1[ci][3] * i13);
    }
}

// ---------------------------------------------------------------------------
extern "C" void kernel_launch(void* const* d_in, const int* in_sizes, int n_in,
                              void* d_out, int out_size, void* d_ws, size_t ws_size,
                              hipStream_t stream)
{
    const float* query = (const float*)d_in[0];
    const float* key_  = (const float*)d_in[1];
    const float* value = (const float*)d_in[2];
    const int* qm  = (const int*)d_in[3];
    const int* kvm = (const int*)d_in[4];
    const float* qconv = (const float*)d_in[5];
    const float* kconv = (const float*)d_in[6];
    const float* vconv = (const float*)d_in[7];
    const float* qnw = (const float*)d_in[8];
    const float* qnb = (const float*)d_in[9];
    const float* knw = (const float*)d_in[10];
    const float* knb = (const float*)d_in[11];
    const float* vnw = (const float*)d_in[12];
    const float* vnb = (const float*)d_in[13];
    const float* wq = (const float*)d_in[14];
    const float* bq = (const float*)d_in[15];
    const float* wk = (const float*)d_in[16];
    const float* bk = (const float*)d_in[17];
    const float* wv = (const float*)d_in[18];
    const float* bv = (const float*)d_in[19];
    const float* wp = (const float*)d_in[20];
    const float* bp = (const float*)d_in[21];

    const size_t MB = 1024 * 1024;
    char* W = (char*)d_ws;
    u8* Xq   = (u8*)(W + 0 * MB);      // LN'd, transposed [b*t][C] fp8
    u8* Xk   = (u8*)(W + 8 * MB);
    u8* Xv   = (u8*)(W + 16 * MB);
    u8* Qt   = (u8*)(W + 24 * MB);     // [b*t][C] fp8 (scaled 0.42466)
    u8* Kt   = (u8*)(W + 32 * MB);     // [b*t][C] fp8 (scaled 0.42466)
    u8* Vb_  = (u8*)(W + 40 * MB);     // [b][C][t] fp8 (kv-masked)
    u8* att_ = (u8*)(W + 48 * MB);     // [b*t][C] fp8 x16
    u8* wq8  = (u8*)(W + 56 * MB);     // fp8, x64
    u8* wk8  = (u8*)(W + 58 * MB);
    u8* wv8  = (u8*)(W + 60 * MB);
    u8* wp8  = (u8*)(W + 62 * MB);     // fp8, x64

    int ntail = out_size - BCT;
    if (ntail < 0) ntail = 0;

    prep_kernel<<<dim3(2824), 512, 0, stream>>>(
        query, key_, value, qconv, kconv, vconv, qm, kvm,
        qnw, qnb, knw, knb, vnw, vnb, Xq, Xk, Xv,
        wq, wk, wv, wp, wq8, wk8, wv8, wp8,
        (float*)d_out + BCT, ntail);

    gemm_qkv_kernel<<<dim3(768), 256, 0, stream>>>(
        Xq, Xk, Xv, wq8, wk8, wv8, bq, bk, bv, Qt, Kt, Vb_, kvm);

    attn_mfma_kernel<<<dim3(512), 256, 0, stream>>>(Qt, Kt, Vb_, att_);

    gemm_out_kernel<<<dim3(256), 256, 0, stream>>>(wp8, att_, bp, (float*)d_out, qm);
}

// Round 21
// 98.266 us; speedup vs baseline: 1.0833x; 1.0833x over previous
//
#include <hip/hip_runtime.h>
#include <math.h>

#define B_ 4
#define C_ 1024
#define T_ 1024
#define H_ 16
#define CH_ 64
#define BCT (B_ * C_ * T_)   // 4194304

typedef __attribute__((ext_vector_type(8))) short s16x8;
typedef __attribute__((ext_vector_type(4))) float f32x4;
typedef __attribute__((ext_vector_type(2))) float f32x2;
typedef unsigned short u16;
typedef unsigned char u8;

#define MFMA8(a, b, c)  __builtin_amdgcn_mfma_f32_16x16x32_fp8_fp8((a), (b), (c), 0, 0, 0)

extern "C" __device__ float __ocml_native_exp2_f32(float);

__device__ __forceinline__ u16 f2bf(float f) {
    union { float f; unsigned u; } v; v.f = f;
    unsigned r = (v.u + 0x7fffu + ((v.u >> 16) & 1u)) >> 16;   // RNE
    return (u16)r;
}

// HW fp8 pack/unpack (gfx940+)
__device__ __forceinline__ unsigned pk4_fp8(float a, float b, float c, float d) {
    int v = 0;
    v = __builtin_amdgcn_cvt_pk_fp8_f32(a, b, v, false);   // bytes 0,1
    v = __builtin_amdgcn_cvt_pk_fp8_f32(c, d, v, true);    // bytes 2,3
    return (unsigned)v;
}
__device__ __forceinline__ u8 f2fp8(float v) {
    return (u8)(__builtin_amdgcn_cvt_pk_fp8_f32(v, v, 0, false) & 0xff);
}

// async global->LDS, 16B per lane; LDS dest = wave-uniform base + lane*16
typedef __attribute__((address_space(3))) unsigned int lds_u32;
typedef __attribute__((address_space(1))) const unsigned int glb_u32;
__device__ __forceinline__ void glds16(const void* g, const void* l_wave_uniform) {
    __builtin_amdgcn_global_load_lds(
        (glb_u32*)(unsigned long long)g,
        (lds_u32*)(unsigned long long)l_wave_uniform, 16, 0, 0);
}

// counted-vmcnt barrier: keep N loads in flight across the barrier (T4)
#define WAIT_BARRIER(N)                                   \
    asm volatile("s_waitcnt vmcnt(" #N ")" ::: "memory"); \
    __builtin_amdgcn_s_barrier();                         \
    __builtin_amdgcn_sched_barrier(0)

// ---------------------------------------------------------------------------
// prep_kernel (r18-proven, 32-t chunks): lnT (384) + wcvt (2048) + tail (8).
// ---------------------------------------------------------------------------
__global__ __launch_bounds__(512) void prep_kernel(
    const float* __restrict__ xq, const float* __restrict__ xk, const float* __restrict__ xv,
    const float* __restrict__ wq3, const float* __restrict__ wk3, const float* __restrict__ wv3,
    const int* __restrict__ qm, const int* __restrict__ kvm,
    const float* __restrict__ qnw, const float* __restrict__ qnb,
    const float* __restrict__ knw, const float* __restrict__ knb,
    const float* __restrict__ vnw, const float* __restrict__ vnb,
    u8* __restrict__ oq, u8* __restrict__ ok, u8* __restrict__ ov,
    const float* __restrict__ w0, const float* __restrict__ w1,
    const float* __restrict__ w2, const float* __restrict__ w3,
    u8* __restrict__ o0, u8* __restrict__ o1, u8* __restrict__ o2, u8* __restrict__ o3,
    float* __restrict__ tail_out, int ntail)
{
    __shared__ __align__(16) u8 tile8[32 * 1040];     // [t][c] fp8x16, stride 1040B
    __shared__ float w3L[3072];                       // conv weights (12KB)
    __shared__ float redw1[8][36], redw2[8][36];      // per-wave partials
    __shared__ float musL[32], rssL[32];

    const int bid = blockIdx.x;
    if (bid >= 384) {
        if (bid >= 2432) {                              // ---- mask_tail
            int i = (bid - 2432) * 512 + threadIdx.x;
            if (i < ntail) tail_out[i] = (qm[i] != 0) ? 1.f : 0.f;
            return;
        }
        // ---- wcvt: 512 blocks per matrix, 4 floats/thread -> fp8 * 64
        const int b2 = bid - 384;
        const int mat = b2 >> 9;
        const int i = ((b2 & 511) * 512 + threadIdx.x) * 4;
        const float* __restrict__ w = (mat == 0) ? w0 : (mat == 1) ? w1
                                     : (mat == 2) ? w2 : w3;
        u8* __restrict__ o = (mat == 0) ? o0 : (mat == 1) ? o1
                            : (mat == 2) ? o2 : o3;
        float4 v = *(const float4*)&w[i];
        *(unsigned*)&o[i] = pk4_fp8(64.f * v.x, 64.f * v.y, 64.f * v.z, 64.f * v.w);
        return;
    }

    // ---- lnT: fused dwconv(k=3,pad=1)+mask -> channel-LN -> transpose fp8
    const int z = bid >> 5;                 // tensor*4 + b
    const int tensor = z >> 2, b = z & 3;
    const float* __restrict__ x   = (tensor == 0) ? xq  : (tensor == 1) ? xk  : xv;
    const float* __restrict__ w3c = (tensor == 0) ? wq3 : (tensor == 1) ? wk3 : wv3;
    const int* __restrict__ msk   = (tensor == 0) ? qm  : kvm;
    const float* __restrict__ wln = (tensor == 0) ? qnw : (tensor == 1) ? knw : vnw;
    const float* __restrict__ bln = (tensor == 0) ? qnb : (tensor == 1) ? knb : vnb;
    u8* __restrict__ xt = (tensor == 0) ? oq : (tensor == 1) ? ok : ov;

    const int t0 = (bid & 31) * 32;

    #pragma unroll
    for (int i = 0; i < 6; ++i) w3L[i * 512 + threadIdx.x] = w3c[i * 512 + threadIdx.x];
    __syncthreads();

    const int tg = threadIdx.x & 7, cs = threadIdx.x >> 3;    // cs 0..63
    const int tbase = t0 + 4 * tg;
    const int4 m4 = *(const int4*)&msk[b * T_ + tbase];
    const float mk0 = m4.x ? 1.f : 0.f;
    const float mk1 = m4.y ? 1.f : 0.f;
    const float mk2 = m4.z ? 1.f : 0.f;
    const float mk3 = m4.w ? 1.f : 0.f;

    float s1a[4] = {0.f, 0.f, 0.f, 0.f};
    float s2a[4] = {0.f, 0.f, 0.f, 0.f};

    #pragma unroll 4
    for (int i = 0; i < 16; ++i) {
        const int c = cs + 64 * i;
        const float* xr = x + ((size_t)(b * C_ + c)) * T_ + tbase;
        const float4 f = *(const float4*)xr;
        float pv = __shfl_up(f.w, 1);
        float nv = __shfl_down(f.x, 1);
        if (tg == 0) pv = (t0 > 0)        ? xr[-1] : 0.f;
        if (tg == 7) nv = (t0 + 32 < T_)  ? xr[4]  : 0.f;
        const float cw0 = w3L[3 * c], cw1 = w3L[3 * c + 1], cw2 = w3L[3 * c + 2];
        const float v0 = (cw0 * pv  + cw1 * f.x + cw2 * f.y) * mk0;
        const float v1 = (cw0 * f.x + cw1 * f.y + cw2 * f.z) * mk1;
        const float v2 = (cw0 * f.y + cw1 * f.z + cw2 * f.w) * mk2;
        const float v3 = (cw0 * f.z + cw1 * f.w + cw2 * nv ) * mk3;
        s1a[0] += v0; s2a[0] += v0 * v0;
        s1a[1] += v1; s2a[1] += v1 * v1;
        s1a[2] += v2; s2a[2] += v2 * v2;
        s1a[3] += v3; s2a[3] += v3 * v3;
        const unsigned pk = pk4_fp8(16.f * v0, 16.f * v1, 16.f * v2, 16.f * v3);
        tile8[(4 * tg + 0) * 1040 + c] = (u8)(pk);
        tile8[(4 * tg + 1) * 1040 + c] = (u8)(pk >> 8);
        tile8[(4 * tg + 2) * 1040 + c] = (u8)(pk >> 16);
        tile8[(4 * tg + 3) * 1040 + c] = (u8)(pk >> 24);
    }

    #pragma unroll
    for (int j = 0; j < 4; ++j) {
        s1a[j] += __shfl_xor(s1a[j], 8);
        s1a[j] += __shfl_xor(s1a[j], 16);
        s1a[j] += __shfl_xor(s1a[j], 32);
        s2a[j] += __shfl_xor(s2a[j], 8);
        s2a[j] += __shfl_xor(s2a[j], 16);
        s2a[j] += __shfl_xor(s2a[j], 32);
    }
    const int lane = threadIdx.x & 63, wv = threadIdx.x >> 6;
    if (lane < 8) {
        float4 a; a.x = s1a[0]; a.y = s1a[1]; a.z = s1a[2]; a.w = s1a[3];
        float4 q; q.x = s2a[0]; q.y = s2a[1]; q.z = s2a[2]; q.w = s2a[3];
        *(float4*)&redw1[wv][4 * lane] = a;
        *(float4*)&redw2[wv][4 * lane] = q;
    }
    __syncthreads();
    if (threadIdx.x < 32) {
        float a = 0.f, q2 = 0.f;
        #pragma unroll
        for (int w = 0; w < 8; ++w) { a += redw1[w][threadIdx.x]; q2 += redw2[w][threadIdx.x]; }
        float m_  = a  * (1.f / C_);
        float var = q2 * (1.f / C_) - m_ * m_;
        musL[threadIdx.x] = m_;
        rssL[threadIdx.x] = rsqrtf(var + 1e-5f);
    }
    __syncthreads();

    #pragma unroll
    for (int it = 0; it < 8; ++it) {
        const int idx = it * 512 + threadIdx.x;
        const int tt = idx >> 7, c0 = (idx & 127) * 8;
        const uint2 pv8 = *(const uint2*)&tile8[tt * 1040 + c0];
        const f32x2 f01 = __builtin_amdgcn_cvt_pk_f32_fp8((int)pv8.x, false);
        const f32x2 f23 = __builtin_amdgcn_cvt_pk_f32_fp8((int)pv8.x, true);
        const f32x2 f45 = __builtin_amdgcn_cvt_pk_f32_fp8((int)pv8.y, false);
        const f32x2 f67 = __builtin_amdgcn_cvt_pk_f32_fp8((int)pv8.y, true);
        const float m_ = musL[tt], rv = rssL[tt];
        const float4 wv0 = *(const float4*)&wln[c0];
        const float4 wv1 = *(const float4*)&wln[c0 + 4];
        const float4 bv0 = *(const float4*)&bln[c0];
        const float4 bv1 = *(const float4*)&bln[c0 + 4];
        const float inv16 = 0.0625f;
        float fv0 = (f01[0] * inv16 - m_) * rv * wv0.x + bv0.x;
        float fv1 = (f01[1] * inv16 - m_) * rv * wv0.y + bv0.y;
        float fv2 = (f23[0] * inv16 - m_) * rv * wv0.z + bv0.z;
        float fv3 = (f23[1] * inv16 - m_) * rv * wv0.w + bv0.w;
        float fv4 = (f45[0] * inv16 - m_) * rv * wv1.x + bv1.x;
        float fv5 = (f45[1] * inv16 - m_) * rv * wv1.y + bv1.y;
        float fv6 = (f67[0] * inv16 - m_) * rv * wv1.z + bv1.z;
        float fv7 = (f67[1] * inv16 - m_) * rv * wv1.w + bv1.w;
        uint2 o;
        o.x = pk4_fp8(fv0, fv1, fv2, fv3);
        o.y = pk4_fp8(fv4, fv5, fv6, fv7);
        *(uint2*)&xt[((size_t)(b * T_ + t0 + tt)) * C_ + c0] = o;
    }
}

// ---------------------------------------------------------------------------
// fp8 MFMA GEMM (NT), 128x128 tile, BK=64 (r18-proven core).
// ---------------------------------------------------------------------------
__device__ __forceinline__ void stage_slab8(
    const u8* __restrict__ gA, const u8* __restrict__ gB,
    u8* lA, u8* lB, int k0, int wave, int lane)
{
    const int rl = lane >> 2, blk = lane & 3;
    #pragma unroll
    for (int i = 0; i < 2; ++i) {
        const int row = wave * 32 + 16 * i + rl;
        const int sb = ((blk ^ ((row >> 1) & 3)) * 16) + k0;
        glds16(gA + (size_t)row * C_ + sb, lA + (wave * 32 + 16 * i) * 64);
        glds16(gB + (size_t)row * C_ + sb, lB + (wave * 32 + 16 * i) * 64);
    }
}

// shared BK=64 fp8 main loop; OUT_F32: 0 = fp8-out (QKV), 1 = f32-out (out-proj)
template<int OUT_F32>
__device__ __forceinline__ void gemm8_core(
    const u8* __restrict__ Ab, const u8* __restrict__ Bb, void* __restrict__ D,
    const float* __restrict__ bias, const int* __restrict__ mask,
    float acc_scale, float scale, int bias_on_n, int m0, int n0)
{
    __shared__ __align__(16) u8 As[3][128 * 64];
    __shared__ __align__(16) u8 Bs[3][128 * 64];
    const int tid = threadIdx.x, lane = tid & 63, wave = tid >> 6;
    const int r = lane & 15, g = lane >> 4;
    const int wm = (wave >> 1) * 64, wn = (wave & 1) * 64;

    f32x4 acc[4][4];
    #pragma unroll
    for (int i = 0; i < 4; ++i)
        #pragma unroll
        for (int j = 0; j < 4; ++j) acc[i][j] = f32x4{0.f, 0.f, 0.f, 0.f};

    stage_slab8(Ab, Bb, As[0], Bs[0], 0, wave, lane);
    stage_slab8(Ab, Bb, As[1], Bs[1], 64, wave, lane);
    WAIT_BARRIER(4);

    const int NK = 16;
    int cur = 0;
    for (int kt = 0; kt < NK; ++kt) {
        int pre = cur + 2; if (pre >= 3) pre -= 3;
        if (kt + 2 < NK)
            stage_slab8(Ab, Bb, As[pre], Bs[pre], (kt + 2) * 64, wave, lane);
        #pragma unroll
        for (int kk = 0; kk < 2; ++kk) {
            long af[4], bf[4];
            #pragma unroll
            for (int mi = 0; mi < 4; ++mi) {
                const int row = wm + 16 * mi + r;
                const int jb = (2 * kk + (g >> 1)) ^ ((row >> 1) & 3);
                af[mi] = *(const long*)&As[cur][row * 64 + jb * 16 + (g & 1) * 8];
            }
            #pragma unroll
            for (int ni = 0; ni < 4; ++ni) {
                const int row = wn + 16 * ni + r;
                const int jb = (2 * kk + (g >> 1)) ^ ((row >> 1) & 3);
                bf[ni] = *(const long*)&Bs[cur][row * 64 + jb * 16 + (g & 1) * 8];
            }
            #pragma unroll
            for (int mi = 0; mi < 4; ++mi)
                #pragma unroll
                for (int ni = 0; ni < 4; ++ni)
                    acc[mi][ni] = MFMA8(af[mi], bf[ni], acc[mi][ni]);
        }
        if (kt + 1 < NK) {
            if (kt + 2 < NK) { WAIT_BARRIER(4); }
            else             { WAIT_BARRIER(0); }
        }
        cur = (cur == 2) ? 0 : cur + 1;
    }

    #pragma unroll
    for (int mi = 0; mi < 4; ++mi) {
        #pragma unroll
        for (int ni = 0; ni < 4; ++ni) {
            const int n = n0 + wn + 16 * ni + r;
            float mk = 1.f;
            if (mask) mk = (mask[n] != 0) ? 1.f : 0.f;
            #pragma unroll
            for (int i = 0; i < 4; ++i) {
                const int m = m0 + wm + 16 * mi + 4 * g + i;
                float v = acc[mi][ni][i] * acc_scale + (bias_on_n ? bias[n] : bias[m]);
                v *= scale * mk;
                if (OUT_F32) ((float*)D)[(size_t)m * 1024 + n] = v;
                else         ((u8*)D)[(size_t)m * 1024 + n] = f2fp8(v);
            }
        }
    }
}

// merged Q/K/V projection, 1-D grid 768, XCD-chunked remap (T1)
__global__ __launch_bounds__(256) void gemm_qkv_kernel(
    const u8* __restrict__ Xq, const u8* __restrict__ Xk, const u8* __restrict__ Xv,
    const u8* __restrict__ Wq, const u8* __restrict__ Wk, const u8* __restrict__ Wv,
    const float* __restrict__ bq, const float* __restrict__ bk, const float* __restrict__ bv,
    u8* __restrict__ Qt, u8* __restrict__ Kt, u8* __restrict__ Vb, const int* __restrict__ kvm)
{
    const int p = blockIdx.x;                      // 0..767
    const int lb = (p & 7) * 96 + (p >> 3);        // bijective (768 % 8 == 0)
    const int z = lb >> 6, yy = (lb >> 3) & 7, xx = lb & 7;
    const int tensor = z >> 2, b = z & 3;
    const size_t off = (size_t)b * (1024 * 1024);
    const float qkscale = 0.42466090f;             // sqrt(0.125*log2e)
    const u8* A = (tensor == 0) ? Xq + off : (tensor == 1) ? Xk + off : Wv;
    const u8* B = (tensor == 0) ? Wq       : (tensor == 1) ? Wk       : Xv + off;
    u8*      D = (tensor == 0) ? Qt + off : (tensor == 1) ? Kt + off : Vb + off;
    const float* bias = (tensor == 0) ? bq : (tensor == 1) ? bk : bv;
    const int* mask = (tensor == 2) ? kvm + (size_t)b * T_ : nullptr;
    const float scale = (tensor == 2) ? 1.f : qkscale;
    const int m0 = yy * 128, n0 = xx * 128;
    gemm8_core<0>(A + (size_t)m0 * C_, B + (size_t)n0 * C_, D,
                  bias, mask, 0.015625f, scale, tensor != 2, m0, n0);
}

// out-proj: fp8 BK=64 core, f32 output.  att fp8 x16, wp fp8 x64 ->
// acc_scale = 1/1024.
__global__ __launch_bounds__(256) void gemm_out_kernel(
    const u8* __restrict__ Wp, const u8* __restrict__ att,
    const float* __restrict__ bp, float* __restrict__ out, const int* __restrict__ qm)
{
    const int p = blockIdx.x;                      // 0..255
    const int lb = (p & 7) * 32 + (p >> 3);        // bijective (256 % 8 == 0)
    const int b = lb >> 6, yy = (lb >> 3) & 7, xx = lb & 7;
    const size_t off = (size_t)b * (1024 * 1024);
    const int m0 = yy * 128, n0 = xx * 128;
    gemm8_core<1>(Wp + (size_t)m0 * C_, att + off + (size_t)n0 * C_, out + off,
                  bp, qm + (size_t)b * T_, 1.f / 1024.f, 1.f, 0, m0, n0);
}

// ---------------------------------------------------------------------------
// fp8 MFMA flash attention (r18-proven): fp8 att x16 output.
// ---------------------------------------------------------------------------
__global__ __launch_bounds__(256) void attn_mfma_kernel(
    const u8* __restrict__ Qt, const u8* __restrict__ Kt, const u8* __restrict__ Vb,
    u8* __restrict__ att)
{
    const int p = blockIdx.x;                      // 0..511
    const int lb = (p & 7) * 64 + (p >> 3);        // bijective (512 % 8 == 0)
    const int bh = lb >> 3, sblk = lb & 7;
    const int b = bh >> 4, h = bh & 15;
    const int lane = threadIdx.x & 63, wave = threadIdx.x >> 6;
    const int r = lane & 15, g = lane >> 4;
    const int hofs = h * 64;
    const int s0 = sblk * 128 + wave * 16;         // second tile at s0+64

    __shared__ __align__(16) u8 Ks[3][64 * 64];    // [t][ch] 4KB
    __shared__ __align__(16) u8 Vs[3][64 * 64];    // [ch][t] 4KB
    __shared__ __align__(16) u8 P8[4][2][16 * 72];

    const u8* qb0 = Qt + ((size_t)(b * T_ + s0 + r)) * C_ + hofs + g * 8;
    const long qf00 = *(const long*)(qb0);
    const long qf01 = *(const long*)(qb0 + 32);
    const long qf10 = *(const long*)(qb0 + (size_t)64 * C_);
    const long qf11 = *(const long*)(qb0 + (size_t)64 * C_ + 32);

    const int rr = 16 * wave + (lane >> 2);
    const int sb16 = ((lane & 3) ^ ((rr >> 1) & 3)) * 16;
    const u8* kg = Kt + ((size_t)(b * T_)) * C_ + hofs;
    const u8* vg = Vb + ((size_t)(b * C_ + hofs)) * T_;

    auto stage = [&](int buf, int t0) {
        glds16(kg + (size_t)(t0 + rr) * C_ + sb16, &Ks[buf][(16 * wave) * 64]);
        glds16(vg + (size_t)rr * T_ + t0 + sb16,   &Vs[buf][(16 * wave) * 64]);
    };

    f32x4 acc0[4], acc1[4];
    #pragma unroll
    for (int ci = 0; ci < 4; ++ci) {
        acc0[ci] = f32x4{0.f, 0.f, 0.f, 0.f};
        acc1[ci] = f32x4{0.f, 0.f, 0.f, 0.f};
    }
    float l0 = 0.f, l1 = 0.f;
    u8* pw0 = &P8[wave][0][0];
    u8* pw1 = &P8[wave][1][0];

    stage(0, 0);
    stage(1, 64);
    WAIT_BARRIER(2);

    const int NT = T_ / 64;
    int cur = 0;
    for (int it = 0; it < NT; ++it) {
        int pre = cur + 2; if (pre >= 3) pre -= 3;
        if (it + 2 < NT) stage(pre, (it + 2) * 64);

        const u8* ks = Ks[cur];
        f32x4 st0[4], st1[4];
        __builtin_amdgcn_s_setprio(1);
        #pragma unroll
        for (int tt = 0; tt < 4; ++tt) {
            const int rowk = 16 * tt + r;
            const int ph = (rowk >> 1) & 3;
            const long ka = *(const long*)
                &ks[rowk * 64 + (((g >> 1) ^ ph) * 16 + (g & 1) * 8)];
            const long kb = *(const long*)
                &ks[rowk * 64 + (((2 + (g >> 1)) ^ ph) * 16 + (g & 1) * 8)];
            f32x4 sa = f32x4{0.f, 0.f, 0.f, 0.f};
            sa = MFMA8(ka, qf00, sa); sa = MFMA8(kb, qf01, sa); st0[tt] = sa;
            f32x4 sb = f32x4{0.f, 0.f, 0.f, 0.f};
            sb = MFMA8(ka, qf10, sb); sb = MFMA8(kb, qf11, sb); st1[tt] = sb;
        }
        __builtin_amdgcn_s_setprio(0);

        #pragma unroll
        for (int tt = 0; tt < 4; ++tt) {
            float a0 = __ocml_native_exp2_f32(st0[tt][0]);
            float a1 = __ocml_native_exp2_f32(st0[tt][1]);
            float a2 = __ocml_native_exp2_f32(st0[tt][2]);
            float a3 = __ocml_native_exp2_f32(st0[tt][3]);
            l0 += (a0 + a1) + (a2 + a3);
            *(unsigned*)&pw0[r * 72 + 16 * tt + 4 * g] = pk4_fp8(a0, a1, a2, a3);
            float b0 = __ocml_native_exp2_f32(st1[tt][0]);
            float b1 = __ocml_native_exp2_f32(st1[tt][1]);
            float b2 = __ocml_native_exp2_f32(st1[tt][2]);
            float b3 = __ocml_native_exp2_f32(st1[tt][3]);
            l1 += (b0 + b1) + (b2 + b3);
            *(unsigned*)&pw1[r * 72 + 16 * tt + 4 * g] = pk4_fp8(b0, b1, b2, b3);
        }

        const u8* vs = Vs[cur];
        __builtin_amdgcn_s_setprio(1);
        #pragma unroll
        for (int kk = 0; kk < 2; ++kk) {
            const long pa0 = *(const long*)&pw0[r * 72 + 32 * kk + 8 * g];
            const long pa1 = *(const long*)&pw1[r * 72 + 32 * kk + 8 * g];
            #pragma unroll
            for (int ci = 0; ci < 4; ++ci) {
                const int rowv = 16 * ci + r;
                const int pv_ = (rowv >> 1) & 3;
                const long vf = *(const long*)
                    &vs[rowv * 64 + (((2 * kk + (g >> 1)) ^ pv_) * 16 + (g & 1) * 8)];
                acc0[ci] = MFMA8(pa0, vf, acc0[ci]);
                acc1[ci] = MFMA8(pa1, vf, acc1[ci]);
            }
        }
        __builtin_amdgcn_s_setprio(0);

        if (it + 1 < NT) {
            if (it + 2 < NT) { WAIT_BARRIER(2); }
            else             { WAIT_BARRIER(0); }
        }
        cur = (cur == 2) ? 0 : cur + 1;
    }

    l0 += __shfl_xor(l0, 16); l0 += __shfl_xor(l0, 32);
    l1 += __shfl_xor(l1, 16); l1 += __shfl_xor(l1, 32);
    // att emitted as fp8 x16 (folded 1/l): inv = 16/l
    const float inv0 = 16.f / l0, inv1 = 16.f / l1;
    const float i00 = __shfl(inv0, 4 * g + 0), i01 = __shfl(inv0, 4 * g + 1);
    const float i02 = __shfl(inv0, 4 * g + 2), i03 = __shfl(inv0, 4 * g + 3);
    const float i10 = __shfl(inv1, 4 * g + 0), i11 = __shfl(inv1, 4 * g + 1);
    const float i12 = __shfl(inv1, 4 * g + 2), i13 = __shfl(inv1, 4 * g + 3);

    u8* ob = att + ((size_t)(b * T_ + s0 + 4 * g)) * C_ + hofs + r;
    #pragma unroll
    for (int ci = 0; ci < 4; ++ci) {
        ob[(size_t)0 * C_ + ci * 16] = f2fp8(acc0[ci][0] * i00);
        ob[(size_t)1 * C_ + ci * 16] = f2fp8(acc0[ci][1] * i01);
        ob[(size_t)2 * C_ + ci * 16] = f2fp8(acc0[ci][2] * i02);
        ob[(size_t)3 * C_ + ci * 16] = f2fp8(acc0[ci][3] * i03);
    }
    u8* ob1 = ob + (size_t)64 * C_;
    #pragma unroll
    for (int ci = 0; ci < 4; ++ci) {
        ob1[(size_t)0 * C_ + ci * 16] = f2fp8(acc1[ci][0] * i10);
        ob1[(size_t)1 * C_ + ci * 16] = f2fp8(acc1[ci][1] * i11);
        ob1[(size_t)2 * C_ + ci * 16] = f2fp8(acc1[ci][2] * i12);
        ob1[(size_t)3 * C_ + ci * 16] = f2fp8(acc1[ci][3] * i13);
    }
}

// ---------------------------------------------------------------------------
extern "C" void kernel_launch(void* const* d_in, const int* in_sizes, int n_in,
                              void* d_out, int out_size, void* d_ws, size_t ws_size,
                              hipStream_t stream)
{
    const float* query = (const float*)d_in[0];
    const float* key_  = (const float*)d_in[1];
    const float* value = (const float*)d_in[2];
    const int* qm  = (const int*)d_in[3];
    const int* kvm = (const int*)d_in[4];
    const float* qconv = (const float*)d_in[5];
    const float* kconv = (const float*)d_in[6];
    const float* vconv = (const float*)d_in[7];
    const float* qnw = (const float*)d_in[8];
    const float* qnb = (const float*)d_in[9];
    const float* knw = (const float*)d_in[10];
    const float* knb = (const float*)d_in[11];
    const float* vnw = (const float*)d_in[12];
    const float* vnb = (const float*)d_in[13];
    const float* wq = (const float*)d_in[14];
    const float* bq = (const float*)d_in[15];
    const float* wk = (const float*)d_in[16];
    const float* bk = (const float*)d_in[17];
    const float* wv = (const float*)d_in[18];
    const float* bv = (const float*)d_in[19];
    const float* wp = (const float*)d_in[20];
    const float* bp = (const float*)d_in[21];

    const size_t MB = 1024 * 1024;
    char* W = (char*)d_ws;
    u8* Xq   = (u8*)(W + 0 * MB);      // LN'd, transposed [b*t][C] fp8
    u8* Xk   = (u8*)(W + 8 * MB);
    u8* Xv   = (u8*)(W + 16 * MB);
    u8* Qt   = (u8*)(W + 24 * MB);     // [b*t][C] fp8 (scaled 0.42466)
    u8* Kt   = (u8*)(W + 32 * MB);     // [b*t][C] fp8 (scaled 0.42466)
    u8* Vb_  = (u8*)(W + 40 * MB);     // [b][C][t] fp8 (kv-masked)
    u8* att_ = (u8*)(W + 48 * MB);     // [b*t][C] fp8 x16
    u8* wq8  = (u8*)(W + 56 * MB);     // fp8, x64
    u8* wk8  = (u8*)(W + 58 * MB);
    u8* wv8  = (u8*)(W + 60 * MB);
    u8* wp8  = (u8*)(W + 62 * MB);     // fp8, x64

    int ntail = out_size - BCT;
    if (ntail < 0) ntail = 0;

    prep_kernel<<<dim3(2440), 512, 0, stream>>>(
        query, key_, value, qconv, kconv, vconv, qm, kvm,
        qnw, qnb, knw, knb, vnw, vnb, Xq, Xk, Xv,
        wq, wk, wv, wp, wq8, wk8, wv8, wp8,
        (float*)d_out + BCT, ntail);

    gemm_qkv_kernel<<<dim3(768), 256, 0, stream>>>(
        Xq, Xk, Xv, wq8, wk8, wv8, bq, bk, bv, Qt, Kt, Vb_, kvm);

    attn_mfma_kernel<<<dim3(512), 256, 0, stream>>>(Qt, Kt, Vb_, att_);

    gemm_out_kernel<<<dim3(256), 256, 0, stream>>>(wp8, att_, bp, (float*)d_out, qm);
}